// Round 10
// baseline (133.625 us; speedup 1.0000x reference)
//
#include <hip/hip_runtime.h>

// Problem dims (fixed by setup_inputs)
constexpr int B = 2, C = 32, H = 96, W = 160, D = 32;
constexpr int HW = H * W;            // 15360
constexpr int NP = B * H * W;        // 30720 pixels
constexpr int WG2 = W / 2;           // 80 two-wide output groups per row
constexpr float EPS = 1e-12f;

// sn packed as 2 x fp16: low = s (sum q*k), high = k2 (sum k*k). nq fp32.
typedef _Float16 f16x2 __attribute__((ext_vector_type(2)));
__device__ inline unsigned pack_f16x2(float a, float b) {
  f16x2 p; p.x = (_Float16)a; p.y = (_Float16)b;
  return __builtin_bit_cast(unsigned, p);
}
__device__ inline float2 unpack_f16x2(unsigned w) {
  f16x2 p = __builtin_bit_cast(f16x2, w);
  return make_float2((float)p.x, (float)p.y);
}

// ---------------------------------------------------------------------------
// Stage 1 (real config: single pass, fp16-packed sn). R4 16-lane structure.
// ---------------------------------------------------------------------------
__global__ __launch_bounds__(256) void dav_stage1(
    const float* __restrict__ q, const float* __restrict__ k,
    unsigned* __restrict__ sn, float* __restrict__ nq) {
  int gt = blockIdx.x * 256 + threadIdx.x;
  int pixel = gt >> 4;   // pixel index in [0, NP)
  int sub = gt & 15;
  int dg = sub >> 1;     // d-group [0,8)
  int ch = sub & 1;      // c-half {0,1}
  int b  = pixel / HW;
  int hw = pixel - b * HW;

  const float* kbase = k + ((size_t)(b * C + ch * 16) * HW + hw) * D + dg * 4;
  const float* qbase = q + (size_t)(b * C + ch * 16) * HW + hw;

  float4 s4 = make_float4(0.f, 0.f, 0.f, 0.f);
  float4 n4 = make_float4(0.f, 0.f, 0.f, 0.f);
  float  nqv = 0.f;

#pragma unroll
  for (int c = 0; c < 16; ++c) {
    float4 k4 = *reinterpret_cast<const float4*>(kbase + (size_t)c * HW * D);
    float  qc = qbase[(size_t)c * HW];
    s4.x = fmaf(qc, k4.x, s4.x);
    s4.y = fmaf(qc, k4.y, s4.y);
    s4.z = fmaf(qc, k4.z, s4.z);
    s4.w = fmaf(qc, k4.w, s4.w);
    n4.x = fmaf(k4.x, k4.x, n4.x);
    n4.y = fmaf(k4.y, k4.y, n4.y);
    n4.z = fmaf(k4.z, k4.z, n4.z);
    n4.w = fmaf(k4.w, k4.w, n4.w);
    nqv  = fmaf(qc, qc, nqv);
  }

  s4.x += __shfl_xor(s4.x, 1);
  s4.y += __shfl_xor(s4.y, 1);
  s4.z += __shfl_xor(s4.z, 1);
  s4.w += __shfl_xor(s4.w, 1);
  n4.x += __shfl_xor(n4.x, 1);
  n4.y += __shfl_xor(n4.y, 1);
  n4.z += __shfl_xor(n4.z, 1);
  n4.w += __shfl_xor(n4.w, 1);
  nqv  += __shfl_xor(nqv, 1);

  if (ch == 0) {
    size_t obase = ((size_t)(b * D + dg * 4)) * HW + hw;  // planar (B,D,H,W)
    sn[obase]          = pack_f16x2(s4.x, n4.x);
    sn[obase + HW]     = pack_f16x2(s4.y, n4.y);
    sn[obase + 2 * HW] = pack_f16x2(s4.z, n4.z);
    sn[obase + 3 * HW] = pack_f16x2(s4.w, n4.w);
    if (dg == 0) nq[pixel] = nqv;
  }
}

// ---------------------------------------------------------------------------
// Stage 2 (R8 structure, fp16 sn): branch-free, all 24 loads staged,
// 2 outputs/thread.
// ---------------------------------------------------------------------------
__global__ __launch_bounds__(256) void dav_stage2(
    const unsigned* __restrict__ sn, const float* __restrict__ nq,
    float* __restrict__ out) {
  int idx = blockIdx.x * 256 + threadIdx.x;   // [0, B*D*H*WG2)
  int g  = idx % WG2;
  int h  = (idx / WG2) % H;
  int bd = idx / (WG2 * H);   // b*D + d
  int b  = bd / D;
  int w0 = g * 2;

  const unsigned* plane  = sn + (size_t)bd * HW;
  const float*    qplane = nq + (size_t)b * HW;

  int hm = (h > 0) ? h - 1 : 0;
  int hp = (h < H - 1) ? h + 1 : H - 1;
  float mt = (h > 0) ? 1.f : 0.f;
  float mb = (h < H - 1) ? 1.f : 0.f;
  int cc[4];
  cc[0] = (w0 > 0) ? w0 - 1 : 0;
  cc[1] = w0;
  cc[2] = w0 + 1;
  cc[3] = (w0 + 2 < W) ? w0 + 2 : W - 1;
  float ml = (w0 > 0) ? 1.f : 0.f;
  float mr = (w0 + 2 < W) ? 1.f : 0.f;

  unsigned sT[4], sM[4], sB[4];
  float    qT[4], qM[4], qB[4];
#pragma unroll
  for (int j = 0; j < 4; ++j) {
    sT[j] = plane[hm * W + cc[j]];
    sM[j] = plane[h  * W + cc[j]];
    sB[j] = plane[hp * W + cc[j]];
    qT[j] = qplane[hm * W + cc[j]];
    qM[j] = qplane[h  * W + cc[j]];
    qB[j] = qplane[hp * W + cc[j]];
  }

  float colS[4], colN[4], colQ[4];
#pragma unroll
  for (int j = 0; j < 4; ++j) {
    float2 vT = unpack_f16x2(sT[j]);
    float2 vM = unpack_f16x2(sM[j]);
    float2 vB = unpack_f16x2(sB[j]);
    colS[j] = mt * vT.x + vM.x + mb * vB.x;
    colN[j] = mt * vT.y + vM.y + mb * vB.y;
    colQ[j] = mt * qT[j] + qM[j] + mb * qB[j];
  }

  float dot0 = ml * colS[0] + colS[1] + colS[2];
  float k20  = ml * colN[0] + colN[1] + colN[2];
  float q20  = ml * colQ[0] + colQ[1] + colQ[2];
  float dot1 = colS[1] + colS[2] + mr * colS[3];
  float k21  = colN[1] + colN[2] + mr * colN[3];
  float q21  = colQ[1] + colQ[2] + mr * colQ[3];

  float o0 = dot0 / (fmaxf(sqrtf(q20), EPS) * fmaxf(sqrtf(k20), EPS));
  float o1 = dot1 / (fmaxf(sqrtf(q21), EPS) * fmaxf(sqrtf(k21), EPS));
  *reinterpret_cast<float2*>(out + (size_t)bd * HW + h * W + w0) =
      make_float2(o0, o1);
}

// ---------------------------------------------------------------------------
// DIAGNOSTIC (runs AFTER the real pipeline): pure sequential float4 stream
// read of k, x6 in-kernel -> enters top-5. Measures the best-case read
// throughput any stage-1 traversal could achieve (same L3-mix as R9's
// stage-1 diag, so logical-BW numbers are comparable).
// 1920 blocks * 256 thr: stride 491520; 7,864,320 float4 = exactly 16/thread.
// ---------------------------------------------------------------------------
constexpr size_t KN4 = (size_t)B * C * HW * D / 4;   // 7,864,320
constexpr int RD = 6;

__global__ __launch_bounds__(256) void diag_read(
    const float4* __restrict__ src, float* __restrict__ sink) {
  size_t tid = (size_t)blockIdx.x * 256 + threadIdx.x;
  size_t stride = (size_t)1920 * 256;     // 491520
  float acc = 0.f;
  int pert = 0;                            // stays 0; opaque to compiler
#pragma unroll 1
  for (int r = 0; r < RD; ++r) {
    asm volatile("" : "+v"(pert));         // no cross-pass CSE
    const float4* s = src + pert;
    float a0 = 0.f, a1 = 0.f, a2 = 0.f, a3 = 0.f;
#pragma unroll 1
    for (size_t i = tid; i < KN4; i += 4 * stride) {
      float4 v0 = s[i];
      float4 v1 = s[i + stride];
      float4 v2 = s[i + 2 * stride];
      float4 v3 = s[i + 3 * stride];
      a0 += v0.x + v0.y + v0.z + v0.w;
      a1 += v1.x + v1.y + v1.z + v1.w;
      a2 += v2.x + v2.y + v2.z + v2.w;
      a3 += v3.x + v3.y + v3.z + v3.w;
    }
    acc += a0 + a1 + a2 + a3;
  }
  sink[tid] = acc;   // deterministic; lives in unused d_ws region
}

extern "C" void kernel_launch(void* const* d_in, const int* in_sizes, int n_in,
                              void* d_out, int out_size, void* d_ws, size_t ws_size,
                              hipStream_t stream) {
  const float* q = (const float*)d_in[0];               // (B,C,H,W)
  const float* k = (const float*)d_in[1];               // (B,C,H,W,D)
  float* out = (float*)d_out;                           // (B,D,H,W)

  // Workspace: sn (u32, NP*D = 3.93 MB) | nq (f32, NP) | ... | diag sink @16MB
  unsigned* sn = (unsigned*)d_ws;
  float*    nq = (float*)(sn + (size_t)NP * D);
  float*    sink = (float*)((char*)d_ws + (64u << 20));

  {
    int threads = NP * 16;                  // 491520
    int blocks = threads / 256;             // 1920
    dav_stage1<<<blocks, 256, 0, stream>>>(q, k, sn, nq);
  }
  {
    int n = B * D * H * WG2;                // 491520
    int blocks = n / 256;                   // 1920
    dav_stage2<<<blocks, 256, 0, stream>>>(sn, nq, out);
  }
  // Diagnostic last (its L3 warming is wiped by the harness fill anyway).
  diag_read<<<1920, 256, 0, stream>>>((const float4*)k, sink);
}

// Round 11
// 32.547 us; speedup vs baseline: 4.1056x; 4.1056x over previous
//
#include <hip/hip_runtime.h>

// Problem dims (fixed by setup_inputs)
constexpr int B = 2, C = 32, H = 96, W = 160, D = 32;
constexpr int HW = H * W;            // 15360
constexpr int NP = B * H * W;        // 30720 pixels
constexpr int WG2 = W / 2;           // 80 two-wide output groups per row
constexpr float EPS = 1e-12f;

// sn packed as 2 x fp16: low = s (sum q*k), high = k2 (sum k*k). nq fp32.
// (validated R9/R10: absmax 9.8e-4 vs threshold 5.6e-3)
typedef _Float16 f16x2 __attribute__((ext_vector_type(2)));
__device__ inline unsigned pack_f16x2(float a, float b) {
  f16x2 p; p.x = (_Float16)a; p.y = (_Float16)b;
  return __builtin_bit_cast(unsigned, p);
}
__device__ inline float2 unpack_f16x2(unsigned w) {
  f16x2 p = __builtin_bit_cast(f16x2, w);
  return make_float2((float)p.x, (float)p.y);
}

// ---------------------------------------------------------------------------
// Stage 1: per-pixel channel reductions (R4 16-lane structure + fp16 pack).
//   sn[(b*D+d)*HW + hw] = pack(sum_c q*k, sum_c k*k)
//   nq[b*HW + hw]       = sum_c q*q
// R10 diag proved the c-strided k-walk matches pure-sequential streaming
// (7.2 vs 7.27 TB/s) -- traversal is at the machine's read ceiling.
// ---------------------------------------------------------------------------
__global__ __launch_bounds__(256) void dav_stage1(
    const float* __restrict__ q, const float* __restrict__ k,
    unsigned* __restrict__ sn, float* __restrict__ nq) {
  int gt = blockIdx.x * 256 + threadIdx.x;
  int pixel = gt >> 4;   // pixel index in [0, NP)
  int sub = gt & 15;
  int dg = sub >> 1;     // d-group [0,8)
  int ch = sub & 1;      // c-half {0,1}
  int b  = pixel / HW;
  int hw = pixel - b * HW;

  const float* kbase = k + ((size_t)(b * C + ch * 16) * HW + hw) * D + dg * 4;
  const float* qbase = q + (size_t)(b * C + ch * 16) * HW + hw;

  float4 s4 = make_float4(0.f, 0.f, 0.f, 0.f);
  float4 n4 = make_float4(0.f, 0.f, 0.f, 0.f);
  float  nqv = 0.f;

#pragma unroll
  for (int c = 0; c < 16; ++c) {
    float4 k4 = *reinterpret_cast<const float4*>(kbase + (size_t)c * HW * D);
    float  qc = qbase[(size_t)c * HW];
    s4.x = fmaf(qc, k4.x, s4.x);
    s4.y = fmaf(qc, k4.y, s4.y);
    s4.z = fmaf(qc, k4.z, s4.z);
    s4.w = fmaf(qc, k4.w, s4.w);
    n4.x = fmaf(k4.x, k4.x, n4.x);
    n4.y = fmaf(k4.y, k4.y, n4.y);
    n4.z = fmaf(k4.z, k4.z, n4.z);
    n4.w = fmaf(k4.w, k4.w, n4.w);
    nqv  = fmaf(qc, qc, nqv);
  }

  s4.x += __shfl_xor(s4.x, 1);
  s4.y += __shfl_xor(s4.y, 1);
  s4.z += __shfl_xor(s4.z, 1);
  s4.w += __shfl_xor(s4.w, 1);
  n4.x += __shfl_xor(n4.x, 1);
  n4.y += __shfl_xor(n4.y, 1);
  n4.z += __shfl_xor(n4.z, 1);
  n4.w += __shfl_xor(n4.w, 1);
  nqv  += __shfl_xor(nqv, 1);

  if (ch == 0) {
    size_t obase = ((size_t)(b * D + dg * 4)) * HW + hw;  // planar (B,D,H,W)
    sn[obase]          = pack_f16x2(s4.x, n4.x);
    sn[obase + HW]     = pack_f16x2(s4.y, n4.y);
    sn[obase + 2 * HW] = pack_f16x2(s4.z, n4.z);
    sn[obase + 3 * HW] = pack_f16x2(s4.w, n4.w);
    if (dg == 0) nq[pixel] = nqv;
  }
}

// ---------------------------------------------------------------------------
// Stage 2 (R8 structure, fp16 sn): branch-free, all 24 loads staged before
// any math (one L2-latency wait), 2 outputs/thread, 30 waves/CU.
// ---------------------------------------------------------------------------
__global__ __launch_bounds__(256) void dav_stage2(
    const unsigned* __restrict__ sn, const float* __restrict__ nq,
    float* __restrict__ out) {
  int idx = blockIdx.x * 256 + threadIdx.x;   // [0, B*D*H*WG2)
  int g  = idx % WG2;
  int h  = (idx / WG2) % H;
  int bd = idx / (WG2 * H);   // b*D + d
  int b  = bd / D;
  int w0 = g * 2;

  const unsigned* plane  = sn + (size_t)bd * HW;
  const float*    qplane = nq + (size_t)b * HW;

  int hm = (h > 0) ? h - 1 : 0;
  int hp = (h < H - 1) ? h + 1 : H - 1;
  float mt = (h > 0) ? 1.f : 0.f;
  float mb = (h < H - 1) ? 1.f : 0.f;
  int cc[4];
  cc[0] = (w0 > 0) ? w0 - 1 : 0;
  cc[1] = w0;
  cc[2] = w0 + 1;
  cc[3] = (w0 + 2 < W) ? w0 + 2 : W - 1;
  float ml = (w0 > 0) ? 1.f : 0.f;
  float mr = (w0 + 2 < W) ? 1.f : 0.f;

  unsigned sT[4], sM[4], sB[4];
  float    qT[4], qM[4], qB[4];
#pragma unroll
  for (int j = 0; j < 4; ++j) {
    sT[j] = plane[hm * W + cc[j]];
    sM[j] = plane[h  * W + cc[j]];
    sB[j] = plane[hp * W + cc[j]];
    qT[j] = qplane[hm * W + cc[j]];
    qM[j] = qplane[h  * W + cc[j]];
    qB[j] = qplane[hp * W + cc[j]];
  }

  float colS[4], colN[4], colQ[4];
#pragma unroll
  for (int j = 0; j < 4; ++j) {
    float2 vT = unpack_f16x2(sT[j]);
    float2 vM = unpack_f16x2(sM[j]);
    float2 vB = unpack_f16x2(sB[j]);
    colS[j] = mt * vT.x + vM.x + mb * vB.x;
    colN[j] = mt * vT.y + vM.y + mb * vB.y;
    colQ[j] = mt * qT[j] + qM[j] + mb * qB[j];
  }

  float dot0 = ml * colS[0] + colS[1] + colS[2];
  float k20  = ml * colN[0] + colN[1] + colN[2];
  float q20  = ml * colQ[0] + colQ[1] + colQ[2];
  float dot1 = colS[1] + colS[2] + mr * colS[3];
  float k21  = colN[1] + colN[2] + mr * colN[3];
  float q21  = colQ[1] + colQ[2] + mr * colQ[3];

  float o0 = dot0 / (fmaxf(sqrtf(q20), EPS) * fmaxf(sqrtf(k20), EPS));
  float o1 = dot1 / (fmaxf(sqrtf(q21), EPS) * fmaxf(sqrtf(k21), EPS));
  *reinterpret_cast<float2*>(out + (size_t)bd * HW + h * W + w0) =
      make_float2(o0, o1);
}

extern "C" void kernel_launch(void* const* d_in, const int* in_sizes, int n_in,
                              void* d_out, int out_size, void* d_ws, size_t ws_size,
                              hipStream_t stream) {
  const float* q = (const float*)d_in[0];               // (B,C,H,W)
  const float* k = (const float*)d_in[1];               // (B,C,H,W,D)
  float* out = (float*)d_out;                           // (B,D,H,W)

  // Workspace: sn (u32 packed 2xfp16, NP*D = 3.93 MB) | nq (f32, NP)
  unsigned* sn = (unsigned*)d_ws;
  float*    nq = (float*)(sn + (size_t)NP * D);

  {
    int threads = NP * 16;                  // 16 lanes per pixel -> 491520
    int blocks = threads / 256;             // 1920 (exact)
    dav_stage1<<<blocks, 256, 0, stream>>>(q, k, sn, nq);
  }
  {
    int n = B * D * H * WG2;                // 491520 threads, 2 outputs each
    int blocks = n / 256;                   // 1920 (exact)
    dav_stage2<<<blocks, 256, 0, stream>>>(sn, nq, out);
  }
}